// Round 7
// baseline (96.303 us; speedup 1.0000x reference)
//
#include <hip/hip_runtime.h>
#include <hip/hip_bf16.h>

#define N_TOT 4096
#define D     512
#define BHALF 2048

// exp(2s) = 2^(s * 2*log2(e))
#define EXP2_SCALE 2.8853900817779268f
// exp(2*S_ii) for a normalized row (S_ii = 1 +- ~5e-3 in fp8; error in the
// final log is ~1e-5 -- negligible vs the 0.166 threshold)
#define E2 7.3890560989306495f

typedef __attribute__((ext_vector_type(4))) float floatx4;

#define AS_GLOBAL(p) ((const __attribute__((address_space(1))) void*)(p))
#define AS_LDS(p)    ((__attribute__((address_space(3))) void*)(p))

// s_waitcnt imm: vmcnt[3:0] | expcnt=7<<4 | lgkmcnt=15<<8 (ignore exp/lgkm)
#define WAITCNT_VM(n) (0xF70 | (n))

// ---------------- kernel 1: normalize rows, cast to fp8 e4m3 --------------
// 1024 blocks x 256 threads; one 64-lane wave per row, no LDS, no barrier.
// Also zeroes rowsum[] and done (ws is re-poisoned to 0xAA every call).
__global__ void normalize_kernel(const float* __restrict__ z_i,
                                 const float* __restrict__ z_j,
                                 unsigned char* __restrict__ zn,
                                 float* __restrict__ rowsum,
                                 unsigned int* __restrict__ done) {
    const int wave = threadIdx.x >> 6, lane = threadIdx.x & 63;
    const int row = blockIdx.x * 4 + wave;
    const float* src = (row < BHALF) ? (z_i + (size_t)row * D)
                                     : (z_j + (size_t)(row - BHALF) * D);
    if (lane == 0) rowsum[row] = 0.0f;
    if (blockIdx.x == 0 && threadIdx.x == 0)
        __hip_atomic_store(done, 0u, __ATOMIC_RELAXED, __HIP_MEMORY_SCOPE_AGENT);
    float4 v0 = ((const float4*)src)[lane];
    float4 v1 = ((const float4*)src)[lane + 64];
    float ss = v0.x*v0.x + v0.y*v0.y + v0.z*v0.z + v0.w*v0.w
             + v1.x*v1.x + v1.y*v1.y + v1.z*v1.z + v1.w*v1.w;
    #pragma unroll
    for (int off = 32; off > 0; off >>= 1) ss += __shfl_xor(ss, off);
    float inv = 1.0f / fmaxf(sqrtf(ss), 1e-8f);
    // pack 4 normalized floats -> 4 x e4m3 bytes (v_cvt_pk_fp8_f32, OCP fn)
    int w0 = __builtin_amdgcn_cvt_pk_fp8_f32(v0.x * inv, v0.y * inv, 0, false);
    w0     = __builtin_amdgcn_cvt_pk_fp8_f32(v0.z * inv, v0.w * inv, w0, true);
    int w1 = __builtin_amdgcn_cvt_pk_fp8_f32(v1.x * inv, v1.y * inv, 0, false);
    w1     = __builtin_amdgcn_cvt_pk_fp8_f32(v1.z * inv, v1.w * inv, w1, true);
    int* dst = (int*)(zn + (size_t)row * D);
    dst[lane]      = w0;
    dst[lane + 64] = w1;
}

// ------ kernel 2: fused symmetric GEMM + exp + row-sum + last-block loss --
// Triangular grid: 528 blocks of 256 threads; block -> (bi, bj), bj>=bi.
// fp8 e4m3, 16x16x32_fp8_fp8 MFMA, triple-buffered LDS, prefetch dist 2.
// Finalize fusion WITHOUT __threadfence (round-4 lesson: agent release
// fences -> per-block buffer_wbl2, ~60 us over 528 blocks). Instead, all
// cross-block data moves via device-coherent ops only (atomicAdd + relaxed
// agent-scope atomic st/ld) and publication rides on the vmcnt(0) drain
// that precedes s_barrier -- no cache writeback is ever required.
__launch_bounds__(256)
__global__ void gemm_fused(const unsigned char* __restrict__ zn,
                           float* __restrict__ rowsum,
                           float* __restrict__ spos,
                           unsigned int* __restrict__ done,
                           float* __restrict__ out) {
    __shared__ unsigned char At[3][128 * 32];   // 4 KB per buffer
    __shared__ unsigned char Bt[3][128 * 32];

    // triangular decode (scalar, <=32 iters)
    int b = blockIdx.x, bi = 0, rowlen = 32;
    while (b >= rowlen) { b -= rowlen; rowlen--; bi++; }
    const int bj = bi + b;
    const int i0 = bi * 128;
    const int j0 = bj * 128;

    const int t = threadIdx.x;
    const int lane = t & 63, wave = t >> 6;
    const int wm = wave & 1, wn = wave >> 1;     // 2x2 waves -> 64x64 each
    const int quad = lane >> 4, l16 = lane & 15;

    // staging: per wave, 32 rows x 32 fp8 bytes = 1 KB = one 64x16B issue.
    const int srow = wave * 32 + (lane >> 1);
    const int scol = (lane & 1) * 16;
    const unsigned char* gA = zn + (size_t)(i0 + srow) * D + scol;
    const unsigned char* gB = zn + (size_t)(j0 + srow) * D + scol;
    const int lo = srow * 32 + scol;             // == wave*1024 + lane*16

    floatx4 acc[4][4] = {};

    // prologue: stage k-tiles 0 and 1 into buffers 0 and 1
    __builtin_amdgcn_global_load_lds(AS_GLOBAL(gA),      AS_LDS(&At[0][lo]), 16, 0, 0);
    __builtin_amdgcn_global_load_lds(AS_GLOBAL(gB),      AS_LDS(&Bt[0][lo]), 16, 0, 0);
    __builtin_amdgcn_global_load_lds(AS_GLOBAL(gA + 32), AS_LDS(&At[1][lo]), 16, 0, 0);
    __builtin_amdgcn_global_load_lds(AS_GLOBAL(gB + 32), AS_LDS(&Bt[1][lo]), 16, 0, 0);

    #pragma unroll
    for (int kt = 0; kt < 16; ++kt) {
        const int cur = kt % 3;
        // own tile-kt DMAs complete (2 newer pairs may stay in flight)
        if (kt < 15) __builtin_amdgcn_s_waitcnt(WAITCNT_VM(2));
        else         __builtin_amdgcn_s_waitcnt(WAITCNT_VM(0));
        __builtin_amdgcn_s_barrier();            // all waves' tile-kt done
        __asm__ volatile("" ::: "memory");       // no LDS-read hoisting
        if (kt < 14) {
            const int nxt = (kt + 2) % 3;
            const int ko = (kt + 2) * 32;
            __builtin_amdgcn_global_load_lds(AS_GLOBAL(gA + ko), AS_LDS(&At[nxt][lo]), 16, 0, 0);
            __builtin_amdgcn_global_load_lds(AS_GLOBAL(gB + ko), AS_LDS(&Bt[nxt][lo]), 16, 0, 0);
        }
        long af[4], bf[4];
        #pragma unroll
        for (int tm = 0; tm < 4; ++tm)
            af[tm] = *(const long*)(&At[cur][(wm*64 + tm*16 + l16) * 32 + quad*8]);
        #pragma unroll
        for (int tn = 0; tn < 4; ++tn)
            bf[tn] = *(const long*)(&Bt[cur][(wn*64 + tn*16 + l16) * 32 + quad*8]);
        #pragma unroll
        for (int tm = 0; tm < 4; ++tm)
            #pragma unroll
            for (int tn = 0; tn < 4; ++tn)
                acc[tm][tn] = __builtin_amdgcn_mfma_f32_16x16x32_fp8_fp8(
                    af[tm], bf[tn], acc[tm][tn], 0, 0, 0);
    }

    // epilogue: e = exp(2s). Row sums -> rows I; column sums -> rows J
    // (off-diagonal tiles; S symmetric). All global writes are coherent ops.
    float cs[4] = {0.f, 0.f, 0.f, 0.f};
    #pragma unroll
    for (int tm = 0; tm < 4; ++tm) {
        float rs[4] = {0.f, 0.f, 0.f, 0.f};
        #pragma unroll
        for (int tn = 0; tn < 4; ++tn)
            #pragma unroll
            for (int r = 0; r < 4; ++r) {
                float e = exp2f(acc[tm][tn][r] * EXP2_SCALE);
                rs[r] += e;
                cs[tn] += e;
            }
        #pragma unroll
        for (int r = 0; r < 4; ++r) {
            float v = rs[r];
            v += __shfl_xor(v, 1);
            v += __shfl_xor(v, 2);
            v += __shfl_xor(v, 4);
            v += __shfl_xor(v, 8);
            if (l16 == 0) {
                int gi = i0 + wm*64 + tm*16 + quad*4 + r;
                atomicAdd(&rowsum[gi], v);
            }
        }
    }
    if (bi != bj) {
        #pragma unroll
        for (int tn = 0; tn < 4; ++tn) {
            float v = cs[tn];
            v += __shfl_xor(v, 16);
            v += __shfl_xor(v, 32);
            if (quad == 0) {
                int gj = j0 + wn*64 + tn*16 + l16;
                atomicAdd(&rowsum[gj], v);
            }
        }
    }
    // positive pairs (j = i + 2048) live exactly in blocks bj == bi+16
    if (bj == bi + 16) {
        #pragma unroll
        for (int tm = 0; tm < 4; ++tm)
            #pragma unroll
            for (int tn = 0; tn < 4; ++tn)
                #pragma unroll
                for (int r = 0; r < 4; ++r) {
                    int li = wm*64 + tm*16 + quad*4 + r;   // local row
                    int lj = wn*64 + tn*16 + l16;          // local col
                    if (li == lj) {
                        float s = acc[tm][tn][r];
                        __hip_atomic_store(&spos[i0 + li],         s,
                            __ATOMIC_RELAXED, __HIP_MEMORY_SCOPE_AGENT);
                        __hip_atomic_store(&spos[i0 + li + BHALF], s,
                            __ATOMIC_RELAXED, __HIP_MEMORY_SCOPE_AGENT);
                    }
                }
    }

    // ---- last-block finalize, writeback-free handshake ----
    // Every store above is a coherent-point op (atomicAdd / agent atomic st).
    // Drain this wave's vmem, barrier (all waves drained), then publish.
    __builtin_amdgcn_s_waitcnt(WAITCNT_VM(0));
    __syncthreads();
    __shared__ unsigned int rank;
    if (t == 0)
        rank = __hip_atomic_fetch_add(done, 1u, __ATOMIC_RELAXED,
                                      __HIP_MEMORY_SCOPE_AGENT);
    __syncthreads();
    if (rank == 527u) {
        float acc2 = 0.f;
        for (int i = t; i < N_TOT; i += 256) {
            float sp = __hip_atomic_load(&spos[i],   __ATOMIC_RELAXED,
                                         __HIP_MEMORY_SCOPE_AGENT);
            float rs = __hip_atomic_load(&rowsum[i], __ATOMIC_RELAXED,
                                         __HIP_MEMORY_SCOPE_AGENT);
            float denom = rs - E2 + exp2f(sp * EXP2_SCALE);
            acc2 += __logf(denom) - 2.0f * sp;
        }
        #pragma unroll
        for (int off = 32; off > 0; off >>= 1) acc2 += __shfl_xor(acc2, off);
        __shared__ float red[4];
        if ((t & 63) == 0) red[t >> 6] = acc2;
        __syncthreads();
        if (t == 0)
            out[0] = (red[0] + red[1] + red[2] + red[3]) / (float)N_TOT;
    }
}

extern "C" void kernel_launch(void* const* d_in, const int* in_sizes, int n_in,
                              void* d_out, int out_size, void* d_ws, size_t ws_size,
                              hipStream_t stream) {
    const float* z_i = (const float*)d_in[0];
    const float* z_j = (const float*)d_in[1];
    float* out = (float*)d_out;

    char* ws = (char*)d_ws;
    unsigned char* zn  = (unsigned char*)ws;                      // 2 MB
    float* rowsum      = (float*)(ws + (size_t)N_TOT * D);        // 16 KB
    float* spos        = rowsum + N_TOT;                          // 16 KB
    unsigned int* done = (unsigned int*)(spos + N_TOT);           // 4 B

    normalize_kernel<<<N_TOT / 4, 256, 0, stream>>>(z_i, z_j, zn, rowsum, done);
    gemm_fused<<<(32 * 33) / 2, 256, 0, stream>>>(zn, rowsum, spos, done, out);
}